// Round 6
// baseline (259.163 us; speedup 1.0000x reference)
//
#include <hip/hip_runtime.h>
#include <hip/hip_bf16.h>

typedef unsigned short u16;
typedef __bf16 bf16x8 __attribute__((ext_vector_type(8)));
typedef float f32x4 __attribute__((ext_vector_type(4)));

#define MEMF() asm volatile("" ::: "memory")

__device__ __forceinline__ u16 f2bf(float f) {
    unsigned int u = __builtin_bit_cast(unsigned int, f);
    unsigned int r = u + 0x7FFFu + ((u >> 16) & 1u);
    return (u16)(r >> 16);
}

__device__ __forceinline__ float bf2f(unsigned int bits16) {
    return __builtin_bit_cast(float, bits16 << 16);
}

__device__ __forceinline__ void gload_lds16(const u16* g, u16* l) {
    __builtin_amdgcn_global_load_lds(
        (const __attribute__((address_space(1))) void*)(g),
        (__attribute__((address_space(3))) void*)(l), 16, 0, 0);
}

// ---------------- fp32 -> bf16 convert, 8 elems/thread ----------------
__global__ __launch_bounds__(256) void cvt_bf16_kernel(
    const float* __restrict__ in, u16* __restrict__ out, int n8)
{
    int i = blockIdx.x * 256 + threadIdx.x;
    if (i >= n8) return;
    const float4* p = (const float4*)in + 2 * (long long)i;
    float4 a = p[0], b = p[1];
    uint4 o;
    o.x = (unsigned)f2bf(a.x) | ((unsigned)f2bf(a.y) << 16);
    o.y = (unsigned)f2bf(a.z) | ((unsigned)f2bf(a.w) << 16);
    o.z = (unsigned)f2bf(b.x) | ((unsigned)f2bf(b.y) << 16);
    o.w = (unsigned)f2bf(b.z) | ((unsigned)f2bf(b.w) << 16);
    ((uint4*)out)[i] = o;
}

// ---- m97-structure bf16 GEMM, C = A[M,K] * B[N,K]^T ----
// BM=BN=128, BK=32, 256 threads = 4 waves (2x2), 64x64 per wave.
// LDS 32KB total ([A0][A1][B0][B1] x 8KB) -> 3-5 blocks/CU: inter-block
// overlap hides barrier/waitcnt stalls (m97/m114). Subtiled LDS
// [rowgrp][kgrp=4][16 lanes][8el]: conflict-free ds_read_b128, linear
// global_load_lds staging. Double-buffered, counted vmcnt(4) (never 0
// mid-loop). XCD-bijective 2D-chunk swizzle (cw x ch rectangle per XCD).
template <bool OUT_F32>
__global__ __launch_bounds__(256) void gemm97(
    const u16* __restrict__ A, const u16* __restrict__ B, void* __restrict__ Cv,
    int lda, int ldb, int ldc, int K,
    long long sAz, long long sBz, long long sCz, int cw, int ch)
{
    __shared__ u16 lds[4 * 4096];      // A buf0, A buf1, B buf0, B buf1
    u16* ldsB = lds + 8192;

    // XCD-bijective swizzle: requires cw | gridDim.x and cw*ch == gx*gy/8
    const int flat = blockIdx.x + gridDim.x * blockIdx.y;
    const int xcd = flat & 7, jj = flat >> 3;
    const int nCx = gridDim.x / cw;
    const int bx = (xcd % nCx) * cw + jj % cw;
    const int by = (xcd / nCx) * ch + jj / cw;

    const int z = blockIdx.z;
    A += (long long)z * sAz;
    B += (long long)z * sBz;

    const int tid = threadIdx.x, lane = tid & 63, wave = tid >> 6;
    const int wr = wave >> 1, wc = wave & 1;
    const int m0 = by << 7, n0 = bx << 7;
    const int NT = K >> 5;             // K-tiles of 32 (NT >= 3)

    // staging: slot s stages 8 contiguous bf16 (16B);
    // logical: row = ((s>>6)<<4)|(s&15), kgrp = (s>>4)&3
    const u16* gA[2];
    const u16* gB[2];
#pragma unroll
    for (int i = 0; i < 2; ++i) {
        int s = tid + i * 256;
        int row = ((s >> 6) << 4) | (s & 15), g = (s >> 4) & 3;
        gA[i] = A + (long long)(m0 + row) * lda + g * 8;
        gB[i] = B + (long long)(n0 + row) * ldb + g * 8;
    }
    auto stage = [&](int kt, int buf) {
#pragma unroll
        for (int i = 0; i < 2; ++i) {
            gload_lds16(gA[i] + (long long)kt * 32, lds  + buf * 4096 + (tid + i * 256) * 8);
            gload_lds16(gB[i] + (long long)kt * 32, ldsB + buf * 4096 + (tid + i * 256) * 8);
        }
    };

    f32x4 acc[4][4] = {};

    // prologue: tile0 -> buf0, tile1 -> buf1; wait tile0 only (4 newest in flight)
    stage(0, 0);
    stage(1, 1);
    asm volatile("s_waitcnt vmcnt(4)" ::: "memory");
    __builtin_amdgcn_s_barrier();
    MEMF();

    for (int kt = 0; kt < NT; ++kt) {
        const int cur = kt & 1;
        // frag base: subtile addr = (rowgrp*64 + lane)*8 ; rowgrp stride = 512 elems
        const u16* sAc = lds  + cur * 4096 + lane * 8;
        const u16* sBc = ldsB + cur * 4096 + lane * 8;

        bf16x8 a[4], b[4];
#pragma unroll
        for (int mi = 0; mi < 4; ++mi)
            a[mi] = *(const bf16x8*)(sAc + (wr * 4 + mi) * 512);
#pragma unroll
        for (int ni = 0; ni < 4; ++ni)
            b[ni] = *(const bf16x8*)(sBc + (wc * 4 + ni) * 512);
#pragma unroll
        for (int mi = 0; mi < 4; ++mi)
#pragma unroll
            for (int ni = 0; ni < 4; ++ni)
                acc[mi][ni] = __builtin_amdgcn_mfma_f32_16x16x32_bf16(
                    a[mi], b[ni], acc[mi][ni], 0, 0, 0);

        MEMF();
        __builtin_amdgcn_s_barrier();          // all waves done reading buf[cur]
        if (kt + 2 < NT) {
            stage(kt + 2, cur);                // overwrite cur; wait kt+1 only
            asm volatile("s_waitcnt vmcnt(4)" ::: "memory");
        } else if (kt + 1 < NT) {
            asm volatile("s_waitcnt vmcnt(0)" ::: "memory");  // tail drain
        }
        __builtin_amdgcn_s_barrier();          // staged/next tile visible
        MEMF();
    }

    // epilogue: C/D frag layout col = lane&15, row = (lane>>4)*4 + j
    const int fl = lane & 15, fg = lane >> 4;
    const int er0 = m0 + wr * 64 + fg * 4;
    const int ec0 = n0 + wc * 64 + fl;
    if constexpr (OUT_F32) {
        float* C = (float*)Cv + (long long)z * sCz;
#pragma unroll
        for (int mi = 0; mi < 4; ++mi)
#pragma unroll
            for (int ni = 0; ni < 4; ++ni)
#pragma unroll
                for (int j = 0; j < 4; ++j)
                    C[(long long)(er0 + mi * 16 + j) * ldc + ec0 + ni * 16] = acc[mi][ni][j];
    } else {
        u16* C = (u16*)Cv + (long long)z * sCz;
#pragma unroll
        for (int mi = 0; mi < 4; ++mi)
#pragma unroll
            for (int ni = 0; ni < 4; ++ni)
#pragma unroll
                for (int j = 0; j < 4; ++j)
                    C[(long long)(er0 + mi * 16 + j) * ldc + ec0 + ni * 16] = f2bf(acc[mi][ni][j]);
    }
}

// ---------------- row softmax over 2048 bf16, in place, scale 1/32 ----------------
__global__ __launch_bounds__(256) void softmax_rows(u16* __restrict__ S)
{
    const long long row = blockIdx.x;
    u16* p = S + row * 2048;
    const int tid = threadIdx.x;
    const int lane = tid & 63, wave = tid >> 6;

    uint4 r4 = ((const uint4*)p)[tid];
    unsigned u[4] = {r4.x, r4.y, r4.z, r4.w};
    float v[8];
    const float scale = 1.0f / 32.0f;
#pragma unroll
    for (int i = 0; i < 4; ++i) {
        v[2 * i]     = bf2f(u[i] & 0xFFFFu) * scale;
        v[2 * i + 1] = __builtin_bit_cast(float, u[i] & 0xFFFF0000u) * scale;
    }
    float mx = v[0];
#pragma unroll
    for (int i = 1; i < 8; ++i) mx = fmaxf(mx, v[i]);
#pragma unroll
    for (int off = 32; off >= 1; off >>= 1) mx = fmaxf(mx, __shfl_xor(mx, off, 64));

    __shared__ float redmax[4], redsum[4];
    if (lane == 0) redmax[wave] = mx;
    __syncthreads();
    mx = fmaxf(fmaxf(redmax[0], redmax[1]), fmaxf(redmax[2], redmax[3]));

    float s = 0.f;
#pragma unroll
    for (int i = 0; i < 8; ++i) { v[i] = __expf(v[i] - mx); s += v[i]; }
#pragma unroll
    for (int off = 32; off >= 1; off >>= 1) s += __shfl_xor(s, off, 64);
    if (lane == 0) redsum[wave] = s;
    __syncthreads();
    s = redsum[0] + redsum[1] + redsum[2] + redsum[3];
    float inv = 1.0f / s;

    uint4 o;
    unsigned ov[4];
#pragma unroll
    for (int i = 0; i < 4; ++i)
        ov[i] = (unsigned)f2bf(v[2 * i] * inv) |
                ((unsigned)f2bf(v[2 * i + 1] * inv) << 16);
    o.x = ov[0]; o.y = ov[1]; o.z = ov[2]; o.w = ov[3];
    ((uint4*)p)[tid] = o;
}

extern "C" void kernel_launch(void* const* d_in, const int* in_sizes, int n_in,
                              void* d_out, int out_size, void* d_ws, size_t ws_size,
                              hipStream_t stream) {
    const float* x  = (const float*)d_in[0];   // [4,2048,1024]
    const float* Wq = (const float*)d_in[1];   // [1024,1024]
    const float* Wk = (const float*)d_in[2];
    const float* Wv = (const float*)d_in[3];
    float* out = (float*)d_out;                // [4,2048,1024] fp32

    const int B = 4, S = 2048, D = 1024;
    const long long MS = (long long)B * S;     // 8192

    // workspace layout (bf16 elements); Sc overlays xb (xb dead after vT GEMM)
    u16* Sc  = (u16*)d_ws;                     // 4*2048*2048
    u16* xb  = Sc;                             // 8192*1024 (first half of Sc)
    u16* wqk = Sc  + (long long)B * S * S;     // 2*1024*1024
    u16* wvb = wqk + 2 * D * D;                // 1024*1024
    u16* qk  = wvb + D * D;                    // 8192*2048
    u16* vT  = qk  + MS * 2 * D;               // 1024*8192
    size_t need = (size_t)2 * ((long long)B * S * S + 3 * D * D + MS * 2 * D + MS * D);
    if (ws_size < need) return;

    // 1) converts
    cvt_bf16_kernel<<<(int)(MS * D / 8 / 256), 256, 0, stream>>>(x, xb, (int)(MS * D / 8));
    cvt_bf16_kernel<<<D * D / 8 / 256, 256, 0, stream>>>(Wq, wqk, D * D / 8);
    cvt_bf16_kernel<<<D * D / 8 / 256, 256, 0, stream>>>(Wk, wqk + D * D, D * D / 8);
    cvt_bf16_kernel<<<D * D / 8 / 256, 256, 0, stream>>>(Wv, wvb, D * D / 8);

    // 2) qk[8192][2048] = xb * [Wq;Wk]^T   grid (16,64)=1024 blocks; chunk 8x16
    gemm97<false><<<dim3(2 * D / 128, (int)(MS / 128), 1), 256, 0, stream>>>(
        xb, wqk, qk, D, D, 2 * D, D, 0, 0, 0, 8, 16);

    // 3) vT[1024][8192] = Wv * xb^T        grid (64,8)=512 blocks; chunk 8x8
    gemm97<false><<<dim3((int)(MS / 128), D / 128, 1), 256, 0, stream>>>(
        wvb, xb, vT, D, D, (int)MS, D, 0, 0, 0, 8, 8);

    // 4) scores Sc_b = q_b * k_b^T         grid (16,16,4)=1024 blocks; chunk 4x8
    gemm97<false><<<dim3(S / 128, S / 128, B), 256, 0, stream>>>(
        qk, qk + D, Sc, 2 * D, 2 * D, S, D,
        (long long)S * 2 * D, (long long)S * 2 * D, (long long)S * S, 4, 8);

    // 5) softmax rows (applies 1/32 scale)
    softmax_rows<<<(int)(B * S), 256, 0, stream>>>(Sc);

    // 6) out_b = P_b * vT_b^T              grid (8,16,4)=512 blocks; chunk 4x4
    gemm97<true><<<dim3(D / 128, S / 128, B), 256, 0, stream>>>(
        Sc, vT, out, S, (int)MS, D, S,
        (long long)S * S, (long long)S, (long long)S * D, 4, 4);
}

// Round 7
// 182.707 us; speedup vs baseline: 1.4185x; 1.4185x over previous
//
#include <hip/hip_runtime.h>
#include <hip/hip_bf16.h>

typedef unsigned short u16;
typedef __bf16 bf16x8 __attribute__((ext_vector_type(8)));
typedef float f32x4 __attribute__((ext_vector_type(4)));

__device__ __forceinline__ u16 f2bf(float f) {
    unsigned int u = __builtin_bit_cast(unsigned int, f);
    unsigned int r = u + 0x7FFFu + ((u >> 16) & 1u);
    return (u16)(r >> 16);
}

__device__ __forceinline__ float bf2f(unsigned int bits16) {
    return __builtin_bit_cast(float, bits16 << 16);
}

__device__ __forceinline__ void gload_lds16(const u16* g, u16* l) {
    __builtin_amdgcn_global_load_lds(
        (const __attribute__((address_space(1))) void*)(g),
        (__attribute__((address_space(3))) void*)(l), 16, 0, 0);
}

// ---------------- fp32 -> bf16 convert, 8 elems/thread ----------------
__global__ __launch_bounds__(256) void cvt_bf16_kernel(
    const float* __restrict__ in, u16* __restrict__ out, int n8)
{
    int i = blockIdx.x * 256 + threadIdx.x;
    if (i >= n8) return;
    const float4* p = (const float4*)in + 2 * (long long)i;
    float4 a = p[0], b = p[1];
    uint4 o;
    o.x = (unsigned)f2bf(a.x) | ((unsigned)f2bf(a.y) << 16);
    o.y = (unsigned)f2bf(a.z) | ((unsigned)f2bf(a.w) << 16);
    o.z = (unsigned)f2bf(b.x) | ((unsigned)f2bf(b.y) << 16);
    o.w = (unsigned)f2bf(b.z) | ((unsigned)f2bf(b.w) << 16);
    ((uint4*)out)[i] = o;
}

// ---- 3 weight matrices in one launch: blockIdx.y picks the source ----
__global__ __launch_bounds__(256) void cvt3_bf16_kernel(
    const float* __restrict__ a, const float* __restrict__ b,
    const float* __restrict__ c, u16* __restrict__ out, int n8per)
{
    int i = blockIdx.x * 256 + threadIdx.x;
    if (i >= n8per) return;
    const float* in = (blockIdx.y == 0) ? a : ((blockIdx.y == 1) ? b : c);
    const float4* p = (const float4*)in + 2 * (long long)i;
    float4 va = p[0], vb = p[1];
    uint4 o;
    o.x = (unsigned)f2bf(va.x) | ((unsigned)f2bf(va.y) << 16);
    o.y = (unsigned)f2bf(va.z) | ((unsigned)f2bf(va.w) << 16);
    o.z = (unsigned)f2bf(vb.x) | ((unsigned)f2bf(vb.y) << 16);
    o.w = (unsigned)f2bf(vb.z) | ((unsigned)f2bf(vb.w) << 16);
    ((uint4*)(out + (long long)blockIdx.y * n8per * 8))[i] = o;
}

// ---- row-sum inverse: inv[i] = 1 / sum(partial[i][0..7]) ----
__global__ __launch_bounds__(256) void inv_rows(
    const float* __restrict__ partial, float* __restrict__ inv, int n)
{
    int i = blockIdx.x * 256 + threadIdx.x;
    if (i >= n) return;
    const float* p = partial + (long long)i * 8;
    float s = 0.f;
#pragma unroll
    for (int k = 0; k < 8; ++k) s += p[k];
    inv[i] = 1.0f / s;
}

// ------- 4-phase bf16 GEMM (r4 structure, best measured), C = A[M,K]*B[N,K]^T ---
// BM=256, BK=64, 512 threads = 8 waves. BN=256: waves 2x4 (128x64 each);
// BN=128: waves 4x2 (64x64 each). LDS subtiled [16-row grp][colgrp=8][16 lanes]
// [8el]: conflict-free ds_read_b128 (measured 0 conflicts), linear
// global_load_lds. 4 phases/K-tile, staged gloads region-staggered, counted
// vmcnt once per tile. XCD-bijective 2D-chunk swizzle (cw x ch per XCD).
// EPI: 0 = plain bf16 C; 1 = C=exp(acc/32) bf16 + row-sum partials to aux
//      (requires gridDim.x colblocks == 8); 2 = f32 C scaled by aux=inv[row].
template <int BN, bool OUT_F32, int EPI>
__global__ __launch_bounds__(512, 2) void gemm4p(
    const u16* __restrict__ A, const u16* __restrict__ B, void* __restrict__ Cv,
    int lda, int ldb, int ldc, int K,
    long long sAz, long long sBz, long long sCz, int cw, int ch,
    float* __restrict__ aux)
{
    constexpr int WC = (BN == 256) ? 4 : 2;        // wave grid cols
    constexpr int ROWS = (BN == 256) ? 128 : 64;   // rows per wave
    constexpr int MI = ROWS / 16;                  // A frags per wave (8 / 4)
    constexpr int MIh = MI / 2;
    constexpr int BLOADS = BN / 64;                // B gloads per thread per tile
    constexpr int BNK = BN * 64;                   // B buffer elems

    extern __shared__ u16 lds[];                   // [A buf0][A buf1][B buf0][B buf1]
    u16* ldsB = lds + 32768;

    // XCD-bijective swizzle: cw x ch rectangle per XCD
    const int flat = blockIdx.x + gridDim.x * blockIdx.y;
    const int xcd = flat & 7, jj = flat >> 3;
    const int nCx = gridDim.x / cw;
    const int bx = (xcd % nCx) * cw + jj % cw;
    const int by = (xcd / nCx) * ch + jj / cw;

    const int z = blockIdx.z;
    A += (long long)z * sAz;
    B += (long long)z * sBz;

    const int tid  = threadIdx.x;
    const int lane = tid & 63;
    const int wave = tid >> 6;
    const int wr = wave / WC, wc = wave % WC;
    const int m0 = by << 8, n0 = bx * BN;
    const int NT = K >> 6;

    // staging: slot s stages 8 contiguous bf16; row=((s>>7)<<4)|(s&15), colgrp=(s>>4)&7
    const u16* gAp[4];
    const u16* gBp[BLOADS];
#pragma unroll
    for (int i = 0; i < 4; ++i) {
        int s = tid + i * 512, row = ((s >> 7) << 4) | (s & 15), g = (s >> 4) & 7;
        gAp[i] = A + (long long)(m0 + row) * lda + g * 8;
    }
#pragma unroll
    for (int i = 0; i < BLOADS; ++i) {
        int s = tid + i * 512, row = ((s >> 7) << 4) | (s & 15), g = (s >> 4) & 7;
        gBp[i] = B + (long long)(n0 + row) * ldb + g * 8;
    }
    auto stA = [&](int kt, int buf, int i) {
        gload_lds16(gAp[i] + (long long)kt * 64, lds + buf * 16384 + (tid + i * 512) * 8);
    };
    auto stB = [&](int kt, int buf, int i) {
        gload_lds16(gBp[i] + (long long)kt * 64, ldsB + buf * BNK + (tid + i * 512) * 8);
    };

    f32x4 acc[MI][4] = {};

    // prologue: tile0 -> buf0, tile1 -> buf1; wait tile0 only
#pragma unroll
    for (int i = 0; i < 4; ++i) stA(0, 0, i);
#pragma unroll
    for (int i = 0; i < BLOADS; ++i) stB(0, 0, i);
#pragma unroll
    for (int i = 0; i < 4; ++i) stA(1, 1, i);
#pragma unroll
    for (int i = 0; i < BLOADS; ++i) stB(1, 1, i);
    if constexpr (BN == 256) asm volatile("s_waitcnt vmcnt(8)" ::: "memory");
    else                     asm volatile("s_waitcnt vmcnt(6)" ::: "memory");
    __builtin_amdgcn_s_barrier();

    for (int kt = 0; kt < NT; ++kt) {
        const int cur = kt & 1;
        const u16* sAc = lds  + cur * 16384 + lane * 8;
        const u16* sBc = ldsB + cur * BNK   + lane * 8;
        const bool st = (kt + 2 < NT);

        bf16x8 a[MIh][2], b0[2][2], b1[2][2];

        // ===== phase 0: read A-lo + B-lo; MFMA Q(0,0) =====
#pragma unroll
        for (int mi = 0; mi < MIh; ++mi)
#pragma unroll
            for (int kk = 0; kk < 2; ++kk)
                a[mi][kk] = *(const bf16x8*)(sAc + ((wr * MI + mi) * 8 + kk * 4) * 128);
#pragma unroll
        for (int ni = 0; ni < 2; ++ni)
#pragma unroll
            for (int kk = 0; kk < 2; ++kk)
                b0[ni][kk] = *(const bf16x8*)(sBc + ((wc * 4 + ni) * 8 + kk * 4) * 128);
        __builtin_amdgcn_s_barrier();
        asm volatile("s_waitcnt lgkmcnt(0)" ::: "memory");
        __builtin_amdgcn_s_setprio(1);
#pragma unroll
        for (int kk = 0; kk < 2; ++kk)
#pragma unroll
            for (int mi = 0; mi < MIh; ++mi)
#pragma unroll
                for (int ni = 0; ni < 2; ++ni)
                    acc[mi][ni] = __builtin_amdgcn_mfma_f32_16x16x32_bf16(
                        a[mi][kk], b0[ni][kk], acc[mi][ni], 0, 0, 0);
        __builtin_amdgcn_s_setprio(0);
        __builtin_amdgcn_s_barrier();

        // ===== phase 1: read B-hi; stage A-lo bands; MFMA Q(0,1) =====
#pragma unroll
        for (int ni = 0; ni < 2; ++ni)
#pragma unroll
            for (int kk = 0; kk < 2; ++kk)
                b1[ni][kk] = *(const bf16x8*)(sBc + ((wc * 4 + 2 + ni) * 8 + kk * 4) * 128);
        if constexpr (BN == 256) {
            if (st) { stA(kt + 2, cur, 0); stA(kt + 2, cur, 2); }
        }
        __builtin_amdgcn_s_barrier();
        asm volatile("s_waitcnt lgkmcnt(0)" ::: "memory");
        __builtin_amdgcn_s_setprio(1);
#pragma unroll
        for (int kk = 0; kk < 2; ++kk)
#pragma unroll
            for (int mi = 0; mi < MIh; ++mi)
#pragma unroll
                for (int ni = 0; ni < 2; ++ni)
                    acc[mi][2 + ni] = __builtin_amdgcn_mfma_f32_16x16x32_bf16(
                        a[mi][kk], b1[ni][kk], acc[mi][2 + ni], 0, 0, 0);
        __builtin_amdgcn_s_setprio(0);
        __builtin_amdgcn_s_barrier();

        // ===== phase 2: read A-hi; stage B-lo bands; MFMA Q(1,0) =====
#pragma unroll
        for (int mi = 0; mi < MIh; ++mi)
#pragma unroll
            for (int kk = 0; kk < 2; ++kk)
                a[mi][kk] = *(const bf16x8*)(sAc + ((wr * MI + MIh + mi) * 8 + kk * 4) * 128);
        if (st) {
            if constexpr (BN == 256) { stB(kt + 2, cur, 0); stB(kt + 2, cur, 1); }
            else                     { stB(kt + 2, cur, 0); }
        }
        __builtin_amdgcn_s_barrier();
        asm volatile("s_waitcnt lgkmcnt(0)" ::: "memory");
        __builtin_amdgcn_s_setprio(1);
#pragma unroll
        for (int kk = 0; kk < 2; ++kk)
#pragma unroll
            for (int mi = 0; mi < MIh; ++mi)
#pragma unroll
                for (int ni = 0; ni < 2; ++ni)
                    acc[MIh + mi][ni] = __builtin_amdgcn_mfma_f32_16x16x32_bf16(
                        a[mi][kk], b0[ni][kk], acc[MIh + mi][ni], 0, 0, 0);
        __builtin_amdgcn_s_setprio(0);
        __builtin_amdgcn_s_barrier();

        // ===== phase 3: stage A-hi + B-hi bands; MFMA Q(1,1); counted vmcnt =====
        if (st) {
            if constexpr (BN == 256) {
                stA(kt + 2, cur, 1); stA(kt + 2, cur, 3);
                stB(kt + 2, cur, 2); stB(kt + 2, cur, 3);
            } else {
                stA(kt + 2, cur, 0); stA(kt + 2, cur, 1);
                stA(kt + 2, cur, 2); stA(kt + 2, cur, 3);
                stB(kt + 2, cur, 1);
            }
        }
        __builtin_amdgcn_s_barrier();
        __builtin_amdgcn_s_setprio(1);
#pragma unroll
        for (int kk = 0; kk < 2; ++kk)
#pragma unroll
            for (int mi = 0; mi < MIh; ++mi)
#pragma unroll
                for (int ni = 0; ni < 2; ++ni)
                    acc[MIh + mi][2 + ni] = __builtin_amdgcn_mfma_f32_16x16x32_bf16(
                        a[mi][kk], b1[ni][kk], acc[MIh + mi][2 + ni], 0, 0, 0);
        __builtin_amdgcn_s_setprio(0);
        if (st) {
            if constexpr (BN == 256) asm volatile("s_waitcnt vmcnt(8)" ::: "memory");
            else                     asm volatile("s_waitcnt vmcnt(6)" ::: "memory");
        } else if (kt + 1 < NT) {
            asm volatile("s_waitcnt vmcnt(0)" ::: "memory");
        }
        __builtin_amdgcn_s_barrier();
    }

    // ---------------- epilogue: C/D layout col = lane&15, row = (lane>>4)*4+j --
    const int fl = lane & 15, fg = lane >> 4;
    const int er0 = m0 + wr * ROWS + fg * 4;
    const int ec0 = n0 + wc * 64 + fl;

    if constexpr (EPI == 1) {
        // P~ = exp(acc/32) -> bf16 C; row-sum partials -> aux[(z*2048+row)*8 + bx]
        u16* C = (u16*)Cv + (long long)z * sCz;
        float lsum[MI][4];
#pragma unroll
        for (int mi = 0; mi < MI; ++mi)
#pragma unroll
            for (int j = 0; j < 4; ++j) {
                float s = 0.f;
#pragma unroll
                for (int ni = 0; ni < 4; ++ni) {
                    float e = __expf(acc[mi][ni][j] * 0.03125f);
                    u16 h = f2bf(e);
                    C[(long long)(er0 + mi * 16 + j) * ldc + ec0 + ni * 16] = h;
                    s += bf2f(h);           // sum the rounded values PV will read
                }
                lsum[mi][j] = s;
            }
        // reduce across the 16 fl-lanes (same rows, different cols)
#pragma unroll
        for (int mi = 0; mi < MI; ++mi)
#pragma unroll
            for (int j = 0; j < 4; ++j)
#pragma unroll
                for (int off = 1; off < 16; off <<= 1)
                    lsum[mi][j] += __shfl_xor(lsum[mi][j], off, 64);
        float (*rsbuf)[4] = reinterpret_cast<float(*)[4]>(lds);
        if (fl == 0) {
#pragma unroll
            for (int mi = 0; mi < MI; ++mi)
#pragma unroll
                for (int j = 0; j < 4; ++j)
                    rsbuf[wr * ROWS + mi * 16 + fg * 4 + j][wc] = lsum[mi][j];
        }
        __syncthreads();
        if (tid < 256) {
            float s = rsbuf[tid][0] + rsbuf[tid][1] + rsbuf[tid][2] + rsbuf[tid][3];
            aux[((long long)z * 2048 + m0 + tid) * 8 + bx] = s;
        }
    } else if constexpr (EPI == 2) {
        // f32 C scaled by inv row-sum
        float* C = (float*)Cv + (long long)z * sCz;
        float iv[MI][4];
#pragma unroll
        for (int mi = 0; mi < MI; ++mi)
#pragma unroll
            for (int j = 0; j < 4; ++j)
                iv[mi][j] = aux[(long long)z * 2048 + er0 + mi * 16 + j];
#pragma unroll
        for (int mi = 0; mi < MI; ++mi)
#pragma unroll
            for (int ni = 0; ni < 4; ++ni)
#pragma unroll
                for (int j = 0; j < 4; ++j)
                    C[(long long)(er0 + mi * 16 + j) * ldc + ec0 + ni * 16] =
                        acc[mi][ni][j] * iv[mi][j];
    } else if constexpr (OUT_F32) {
        float* C = (float*)Cv + (long long)z * sCz;
#pragma unroll
        for (int mi = 0; mi < MI; ++mi)
#pragma unroll
            for (int ni = 0; ni < 4; ++ni)
#pragma unroll
                for (int j = 0; j < 4; ++j)
                    C[(long long)(er0 + mi * 16 + j) * ldc + ec0 + ni * 16] = acc[mi][ni][j];
    } else {
        u16* C = (u16*)Cv + (long long)z * sCz;
#pragma unroll
        for (int mi = 0; mi < MI; ++mi)
#pragma unroll
            for (int ni = 0; ni < 4; ++ni)
#pragma unroll
                for (int j = 0; j < 4; ++j)
                    C[(long long)(er0 + mi * 16 + j) * ldc + ec0 + ni * 16] = f2bf(acc[mi][ni][j]);
    }
}

extern "C" void kernel_launch(void* const* d_in, const int* in_sizes, int n_in,
                              void* d_out, int out_size, void* d_ws, size_t ws_size,
                              hipStream_t stream) {
    const float* x  = (const float*)d_in[0];   // [4,2048,1024]
    const float* Wq = (const float*)d_in[1];   // [1024,1024]
    const float* Wk = (const float*)d_in[2];
    const float* Wv = (const float*)d_in[3];
    float* out = (float*)d_out;                // [4,2048,1024] fp32

    const int B = 4, S = 2048, D = 1024;
    const long long MS = (long long)B * S;     // 8192

    // workspace layout (bf16 elements); Sc overlays xb (xb dead after vT GEMM)
    u16* Sc  = (u16*)d_ws;                     // 4*2048*2048
    u16* xb  = Sc;                             // 8192*1024 (first half of Sc)
    u16* wqk = Sc  + (long long)B * S * S;     // 2*1024*1024 (Wq,Wk) then Wv
    u16* wvb = wqk + 2 * D * D;                // 1024*1024 (contiguous after wqk)
    u16* qk  = wvb + D * D;                    // 8192*2048
    u16* vT  = qk  + MS * 2 * D;               // 1024*8192
    float* partial = (float*)(vT + MS * D);    // 8192*8 f32
    float* inv     = partial + (long long)MS * 8;   // 8192 f32
    size_t need = (size_t)2 * ((long long)B * S * S + 3 * D * D + MS * 2 * D + MS * D)
                + (size_t)4 * (MS * 8 + MS);
    if (ws_size < need) return;

    hipFuncSetAttribute(reinterpret_cast<const void*>(&gemm4p<256, false, 0>),
                        hipFuncAttributeMaxDynamicSharedMemorySize, 131072);
    hipFuncSetAttribute(reinterpret_cast<const void*>(&gemm4p<128, false, 0>),
                        hipFuncAttributeMaxDynamicSharedMemorySize, 98304);
    hipFuncSetAttribute(reinterpret_cast<const void*>(&gemm4p<256, false, 1>),
                        hipFuncAttributeMaxDynamicSharedMemorySize, 131072);
    hipFuncSetAttribute(reinterpret_cast<const void*>(&gemm4p<128, true, 2>),
                        hipFuncAttributeMaxDynamicSharedMemorySize, 98304);

    // 1) converts: x (grid 4096), weights (grid 512 x 3)
    cvt_bf16_kernel<<<(int)(MS * D / 8 / 256), 256, 0, stream>>>(x, xb, (int)(MS * D / 8));
    cvt3_bf16_kernel<<<dim3(D * D / 8 / 256, 3, 1), 256, 0, stream>>>(
        Wq, Wk, Wv, wqk, D * D / 8);

    // 2) qk[8192][2048] = xb * [Wq;Wk]^T   grid (8,32); XCD chunk 8x4
    gemm4p<256, false, 0><<<dim3(2 * D / 256, (int)(MS / 256), 1), 512, 131072, stream>>>(
        xb, wqk, qk, D, D, 2 * D, D, 0, 0, 0, 8, 4, nullptr);

    // 3) vT[1024][8192] = Wv * xb^T        grid (64,4); XCD chunk 8x4
    gemm4p<128, false, 0><<<dim3((int)(MS / 128), D / 256, 1), 512, 98304, stream>>>(
        wvb, xb, vT, D, D, (int)MS, D, 0, 0, 0, 8, 4, nullptr);

    // 4) P~ = exp(q k^T / 32) + row partials   grid (8,8,4); XCD chunk 2x4
    gemm4p<256, false, 1><<<dim3(S / 256, S / 256, B), 512, 131072, stream>>>(
        qk, qk + D, Sc, 2 * D, 2 * D, S, D,
        (long long)S * 2 * D, (long long)S * 2 * D, (long long)S * S, 2, 4, partial);

    // 5) inv[row] = 1 / sum_k partial
    inv_rows<<<(int)(MS / 256), 256, 0, stream>>>(partial, inv, (int)MS);

    // 6) out_b = (P~_b * vT_b^T) * inv     grid (8,8,4); XCD chunk 4x2; fp32 out
    gemm4p<128, true, 2><<<dim3(D / 128, S / 256, B), 512, 98304, stream>>>(
        Sc, vT, out, S, (int)MS, D, S,
        (long long)S * S, (long long)S, (long long)S * D, 4, 2, inv);
}